// Round 8
// baseline (208.308 us; speedup 1.0000x reference)
//
#include <hip/hip_runtime.h>
#include <math.h>

#define SIGMA_BOOST 2.0f
#define EPSILON 1e-6f

// native clang vector type — required for __builtin_nontemporal_load/store
typedef float vfloat4 __attribute__((ext_vector_type(4)));

// ---------------------------------------------------------------------------
// Pre-pass: per-t parameters -> float4 {mean_row, mean_col, sigma, pvalue}
//   mean  = sigmoid(pmean) * (N-1)
//   sigma = (softplus(psigma + SIGMA_BOOST) + EPS) * N
// ---------------------------------------------------------------------------
__global__ void params_kernel(const float2* __restrict__ pmeans,
                              const float* __restrict__ psigmas,
                              const float* __restrict__ pvalues,
                              float4* __restrict__ params, int N) {
    int t = blockIdx.x * blockDim.x + threadIdx.x;
    if (t >= N) return;
    float2 pm = pmeans[t];
    float scale = (float)(N - 1);
    float m0 = __fmul_rn(__fdiv_rn(1.0f, __fadd_rn(1.0f, expf(-pm.x))), scale);
    float m1 = __fmul_rn(__fdiv_rn(1.0f, __fadd_rn(1.0f, expf(-pm.y))), scale);
    float z  = __fadd_rn(psigmas[t], SIGMA_BOOST);
    float sp = __fadd_rn(fmaxf(z, 0.0f), log1pf(expf(-fabsf(z))));
    float sg = __fmul_rn(__fadd_rn(sp, EPSILON), (float)N);
    params[t] = make_float4(m0, m1, sg, pvalues[t]);
}

// ---------------------------------------------------------------------------
// Round 8 — STRUCTURAL fix: move the gather off the vmcnt stream.
// r4/r5/r6/r7 all converged at 41-44 us (~192 cyc/wave-iter = one L2-hit
// latency exposed per iteration): the x-gather shares the in-order vmcnt
// counter with the streaming loads, and the compiler re-sinks every
// software-pipeline attempt (VGPR stuck at 32). Instead of fighting the
// scheduler:
//   - x row staged in LDS (64 KB only -> 2 blocks/CU, 32 waves preserved;
//     unlike r3 which kept BOTH x and y in LDS and lost occupancy).
//     The gather becomes ds_read_b32 on lgkmcnt: ~120 cyc, independent of
//     vmem, counted-waited trivially. 80% of reads are same-address
//     broadcasts (clamped cols) = free.
//   - y accumulated with fire-and-forget GLOBAL atomicAdd (no return value
//     -> never waits). Only ~20% mid-lanes are active (rows 0/N-1 stay in
//     registers via the verified peel). Block zeroes its own private y-row
//     first; __syncthreads orders the stores before any atomic.
// Per-sample chain: prefetched stream load -> VALU -> ds_read -> atomic
// issue. Nothing drains vmcnt in the loop. Numerics bit-identical through
// index computation; accumulation order change is within atomic
// nondeterminism already present.
// ---------------------------------------------------------------------------
__device__ __forceinline__ void sample_g(
        const float4 p, const float n0, const float n1,
        const float* __restrict__ lx, float* __restrict__ yb,
        const int iN1, const float fN1, float& acc0, float& accE) {
    // sample = mean + sigma*noise, deliberately UNFUSED (match numpy rounding)
    float s0 = __fadd_rn(p.x, __fmul_rn(p.z, n0));
    float s1 = __fadd_rn(p.y, __fmul_rn(p.z, n1));
    // np.round = half-to-even = rintf; clamp in float, exact int cvt
    int row = (int)fminf(fmaxf(rintf(s0), 0.0f), fN1);
    int col = (int)fminf(fmaxf(rintf(s1), 0.0f), fN1);
    float xv = lx[col];                         // ds_read (lgkmcnt, cheap)
    float ctr = __fmul_rn(p.w, xv);
    bool lo = (row == 0);
    bool hi = (row == iN1);
    if (!(lo | hi)) atomicAdd(&yb[row], ctr);   // global, fire-and-forget
    acc0 = __fadd_rn(acc0, lo ? ctr : 0.0f);    // cndmask, branchless
    accE = __fadd_rn(accE, hi ? ctr : 0.0f);
}

// ---------------------------------------------------------------------------
// One block per batch row. LDS = x-row copy (exactly 64 KB at N=16384);
// 2 blocks/CU, 32 waves/CU. 4 samples per step, noise+params prefetched one
// step ahead (benign now: the vmcnt stream holds only coalesced loads).
// ---------------------------------------------------------------------------
template <bool INLINE_PARAMS>
__launch_bounds__(1024, 8)
__global__ void contract_kernel(const float* __restrict__ x,
                                const float2* __restrict__ noise,
                                const float4* __restrict__ params,
                                const float2* __restrict__ pmeans,
                                const float* __restrict__ psigmas,
                                const float* __restrict__ pvalues,
                                float* __restrict__ y, int N) {
    extern __shared__ float lx[];
    const int b = blockIdx.x;
    const int tid = threadIdx.x;
    const int nthr = blockDim.x;

    const float* xb = x + (size_t)b * N;
    float* yb = y + (size_t)b * N;

    // stage x-row into LDS and zero this block's private y-row
    if ((N & 3) == 0) {
        const int n4 = N >> 2;
        vfloat4* lx4 = (vfloat4*)lx;
        const vfloat4* xb4 = (const vfloat4*)xb;
        vfloat4* yb4 = (vfloat4*)yb;
        const vfloat4 vz = {0.f, 0.f, 0.f, 0.f};
        for (int i = tid; i < n4; i += nthr) {
            lx4[i] = xb4[i];
            yb4[i] = vz;               // regular store: keep lines L2-hot
        }
    } else {
        for (int i = tid; i < N; i += nthr) {
            lx[i] = xb[i];
            yb[i] = 0.0f;
        }
    }
    __syncthreads();   // stores drained (vmcnt0) before any atomic RMW

    const float fN1 = (float)(N - 1);
    const int iN1 = N - 1;
    float acc0 = 0.0f, accE = 0.0f;

    if (!INLINE_PARAMS && ((N >> 1) % (2 * nthr)) == 0) {
        // ---- fast path: 4 t's per step, noise+params prefetched 1 ahead ----
        const vfloat4* nb4 = (const vfloat4*)(noise + (size_t)b * N);  // N/2
        const int npairs = N >> 1;
        const int steps = npairs / (2 * nthr);
        int q0 = tid, q1 = tid + nthr;
        vfloat4 nzA = __builtin_nontemporal_load(&nb4[q0]);
        vfloat4 nzB = __builtin_nontemporal_load(&nb4[q1]);
        float4 pa = params[2 * q0];
        float4 pb = params[2 * q0 + 1];
        float4 pc = params[2 * q1];
        float4 pd = params[2 * q1 + 1];
        for (int s = 0; s < steps; ++s) {
            const vfloat4 cA = nzA, cB = nzB;
            const float4 qa = pa, qb = pb, qc = pc, qd = pd;
            q0 += 2 * nthr; q1 += 2 * nthr;
            if (s + 1 < steps) {               // uniform branch (cheap)
                nzA = __builtin_nontemporal_load(&nb4[q0]);
                nzB = __builtin_nontemporal_load(&nb4[q1]);
                pa = params[2 * q0];
                pb = params[2 * q0 + 1];
                pc = params[2 * q1];
                pd = params[2 * q1 + 1];
            }
            sample_g(qa, cA.x, cA.y, lx, yb, iN1, fN1, acc0, accE);
            sample_g(qb, cA.z, cA.w, lx, yb, iN1, fN1, acc0, accE);
            sample_g(qc, cB.x, cB.y, lx, yb, iN1, fN1, acc0, accE);
            sample_g(qd, cB.z, cB.w, lx, yb, iN1, fN1, acc0, accE);
        }
    } else {
        // ---- generic / inline-params fallback (same structure) -------------
        const float2* nb = noise + (size_t)b * N;
        for (int t = tid; t < N; t += nthr) {
            float4 p;
            if (INLINE_PARAMS) {
                float2 pm = pmeans[t];
                float scale = (float)(N - 1);
                p.x = __fmul_rn(__fdiv_rn(1.0f, __fadd_rn(1.0f, expf(-pm.x))), scale);
                p.y = __fmul_rn(__fdiv_rn(1.0f, __fadd_rn(1.0f, expf(-pm.y))), scale);
                float z  = __fadd_rn(psigmas[t], SIGMA_BOOST);
                float sp = __fadd_rn(fmaxf(z, 0.0f), log1pf(expf(-fabsf(z))));
                p.z = __fmul_rn(__fadd_rn(sp, EPSILON), (float)N);
                p.w = pvalues[t];
            } else {
                p = params[t];
            }
            float2 nz = nb[t];
            sample_g(p, nz.x, nz.y, lx, yb, iN1, fN1, acc0, accE);
        }
    }

    // fold register accumulators: wave shfl-reduce, one global atomic per wave
    for (int off = 32; off > 0; off >>= 1) {
        acc0 = __fadd_rn(acc0, __shfl_down(acc0, off, 64));
        accE = __fadd_rn(accE, __shfl_down(accE, off, 64));
    }
    if ((tid & 63) == 0) {
        atomicAdd(&yb[0], acc0);
        atomicAdd(&yb[iN1], accE);
    }
    // no write-out loop: y was accumulated in place
}

extern "C" void kernel_launch(void* const* d_in, const int* in_sizes, int n_in,
                              void* d_out, int out_size, void* d_ws, size_t ws_size,
                              hipStream_t stream) {
    const float*  x       = (const float*)d_in[0];
    const float2* noise   = (const float2*)d_in[1];
    const float2* pmeans  = (const float2*)d_in[2];
    const float*  psigmas = (const float*)d_in[3];
    const float*  pvalues = (const float*)d_in[4];
    float* y = (float*)d_out;

    const int N = in_sizes[3];          // psigmas is (N,)
    const int B = in_sizes[0] / N;      // x is (B,N)

    const size_t params_bytes = (size_t)N * sizeof(float4);
    const bool use_ws = (ws_size >= params_bytes) && (d_ws != nullptr);

    const int block = 1024;
    const size_t lds_bytes = (size_t)N * sizeof(float);  // 64 KB at N=16384

    if (use_ws) {
        float4* params = (float4*)d_ws;
        params_kernel<<<(N + 255) / 256, 256, 0, stream>>>(pmeans, psigmas,
                                                           pvalues, params, N);
        contract_kernel<false><<<B, block, lds_bytes, stream>>>(
            x, noise, params, nullptr, nullptr, nullptr, y, N);
    } else {
        contract_kernel<true><<<B, block, lds_bytes, stream>>>(
            x, noise, nullptr, pmeans, psigmas, pvalues, y, N);
    }
}

// Round 9
// 152.217 us; speedup vs baseline: 1.3685x; 1.3685x over previous
//
#include <hip/hip_runtime.h>
#include <math.h>

#define SIGMA_BOOST 2.0f
#define EPSILON 1e-6f

// native clang vector type (asm "=v" on it yields a VGPR quad)
typedef float vfloat4 __attribute__((ext_vector_type(4)));

// counted vmem wait + scheduler fence (rule #18: hipcc hoists register-only
// uses past inline-asm waitcnt unless a sched_barrier(0) follows)
#define WAITV(n)                                                   \
    do {                                                           \
        asm volatile("s_waitcnt vmcnt(" #n ")" ::: "memory");      \
        __builtin_amdgcn_sched_barrier(0);                         \
    } while (0)

// ---------------------------------------------------------------------------
// Pre-pass: per-t parameters -> float4 {mean_row, mean_col, sigma, pvalue}
// ---------------------------------------------------------------------------
__global__ void params_kernel(const float2* __restrict__ pmeans,
                              const float* __restrict__ psigmas,
                              const float* __restrict__ pvalues,
                              float4* __restrict__ params, int N) {
    int t = blockIdx.x * blockDim.x + threadIdx.x;
    if (t >= N) return;
    float2 pm = pmeans[t];
    float scale = (float)(N - 1);
    float m0 = __fmul_rn(__fdiv_rn(1.0f, __fadd_rn(1.0f, expf(-pm.x))), scale);
    float m1 = __fmul_rn(__fdiv_rn(1.0f, __fadd_rn(1.0f, expf(-pm.y))), scale);
    float z  = __fadd_rn(psigmas[t], SIGMA_BOOST);
    float sp = __fadd_rn(fmaxf(z, 0.0f), log1pf(expf(-fabsf(z))));
    float sg = __fmul_rn(__fadd_rn(sp, EPSILON), (float)N);
    params[t] = make_float4(m0, m1, sg, pvalues[t]);
}

// ---------------------------------------------------------------------------
// Round 9 — force gather MLP with inline asm.
// Diagnosis: waves stall ~98%; Little's law on the 33K gather lane-requests
// per CU at ~300cyc L2 latency gives ~1 gather instr in flight per wave.
// r7's source-level pipeline was collapsed by hipcc (VGPR pinned at 32 by the
// launch_bounds(1024,8) budget). Here ALL main-loop vmem is asm volatile
// (order-pinned, un-collapsible) with hand-counted vmcnt:
//   8 fully-unrolled phases; phase k:
//     idx(k+1) from L(k+1)   [retired by phase k-1's wait]
//     issue G(k+1): 2 gathers (asm global_load_dword)
//     issue L(k+3): 3 wide loads (asm global_load_dwordx4)  [k<5]
//     s_waitcnt vmcnt(5)     [retires G(k), L(k+2); leaves G(k+1)+L(k+3)]
//     commit k: masked LDS atomics + register peel (r6-verified numerics)
// Steady state: 10 vmem ops outstanding per thread; vmcnt never 0 mid-loop.
// ---------------------------------------------------------------------------
template <bool INLINE_PARAMS>
__launch_bounds__(1024, 8)
__global__ void contract_kernel(const float* __restrict__ x,
                                const float2* __restrict__ noise,
                                const float4* __restrict__ params,
                                const float2* __restrict__ pmeans,
                                const float* __restrict__ psigmas,
                                const float* __restrict__ pvalues,
                                float* __restrict__ y, int N) {
    extern __shared__ float ly[];
    const int b = blockIdx.x;
    const int tid = threadIdx.x;
    const int nthr = blockDim.x;

    // zero LDS accumulator (vectorized)
    float4* ly4 = (float4*)ly;
    const int n4 = N >> 2;
    for (int i = tid; i < n4; i += nthr) ly4[i] = make_float4(0.f, 0.f, 0.f, 0.f);
    __syncthreads();

    const float* xb = x + (size_t)b * N;
    const float fN1 = (float)(N - 1);
    const int iN1 = N - 1;
    float acc0 = 0.0f, accE = 0.0f;

    const int npairs = N >> 1;
    const bool fast = !INLINE_PARAMS && (npairs % nthr) == 0 &&
                      (npairs / nthr) == 8;

    if (fast) {
        const vfloat4* nb4 = (const vfloat4*)(noise + (size_t)b * N); // N/2
        const vfloat4* pp  = (const vfloat4*)params;

        // per-phase state (constant-indexed after full unroll -> registers)
        vfloat4 nzv[8], pav[8], pbv[8];
        float   xv0v[8], xv1v[8], w0v[8], w1v[8];
        int     r0v[8], r1v[8];

        auto issueL = [&](int k) {
            unsigned long long a_nz =
                (unsigned long long)(nb4 + (size_t)k * nthr + tid);
            unsigned long long a_pa =
                (unsigned long long)(pp + 2 * ((size_t)k * nthr + tid));
            unsigned long long a_pb = a_pa + 16ull;
            asm volatile("global_load_dwordx4 %0, %1, off"
                         : "=v"(nzv[k]) : "v"(a_nz));
            asm volatile("global_load_dwordx4 %0, %1, off"
                         : "=v"(pav[k]) : "v"(a_pa));
            asm volatile("global_load_dwordx4 %0, %1, off"
                         : "=v"(pbv[k]) : "v"(a_pb));
        };

        auto issueG = [&](int k) {
            vfloat4 nz = nzv[k], pa = pav[k], pb = pbv[k];
            // sample = mean + sigma*noise, deliberately UNFUSED (numpy match)
            float s0 = __fadd_rn(pa.x, __fmul_rn(pa.z, nz.x));
            float s1 = __fadd_rn(pa.y, __fmul_rn(pa.z, nz.y));
            float s2 = __fadd_rn(pb.x, __fmul_rn(pb.z, nz.z));
            float s3 = __fadd_rn(pb.y, __fmul_rn(pb.z, nz.w));
            // np.round = half-to-even = rintf; clamp in float, exact int cvt
            int r0 = (int)fminf(fmaxf(rintf(s0), 0.0f), fN1);
            int c0 = (int)fminf(fmaxf(rintf(s1), 0.0f), fN1);
            int r1 = (int)fminf(fmaxf(rintf(s2), 0.0f), fN1);
            int c1 = (int)fminf(fmaxf(rintf(s3), 0.0f), fN1);
            r0v[k] = r0; r1v[k] = r1; w0v[k] = pa.w; w1v[k] = pb.w;
            unsigned long long a0 = (unsigned long long)(xb + c0);
            unsigned long long a1 = (unsigned long long)(xb + c1);
            asm volatile("global_load_dword %0, %1, off"
                         : "=v"(xv0v[k]) : "v"(a0));
            asm volatile("global_load_dword %0, %1, off"
                         : "=v"(xv1v[k]) : "v"(a1));
        };

        auto commit = [&](int k) {
            float ctr0 = __fmul_rn(w0v[k], xv0v[k]);
            float ctr1 = __fmul_rn(w1v[k], xv1v[k]);
            int r0 = r0v[k], r1 = r1v[k];
            bool lo0 = (r0 == 0), hi0 = (r0 == iN1);
            bool lo1 = (r1 == 0), hi1 = (r1 == iN1);
            if (!(lo0 | hi0)) atomicAdd(&ly[r0], ctr0);  // ~20% lanes
            if (!(lo1 | hi1)) atomicAdd(&ly[r1], ctr1);
            acc0 = __fadd_rn(acc0, lo0 ? ctr0 : 0.0f);
            accE = __fadd_rn(accE, hi0 ? ctr0 : 0.0f);
            acc0 = __fadd_rn(acc0, lo1 ? ctr1 : 0.0f);
            accE = __fadd_rn(accE, hi1 ? ctr1 : 0.0f);
        };

        // ---- prologue ------------------------------------------------------
        issueL(0); issueL(1); issueL(2);     // 9 ops outstanding
        WAITV(6);                            // L0 done (L1,L2 younger)
        issueG(0);                           // idx(0) + 2 gathers
        WAITV(5);                            // L1 done (L2,G0 = 5 younger)

        // ---- 8 unrolled phases --------------------------------------------
#pragma unroll
        for (int k = 0; k < 8; ++k) {
            if (k == 6) WAITV(2);            // retire L(7) (leaves G(6))
            if (k < 7)  issueG(k + 1);       // needs L(k+1): retired
            if (k < 5)  issueL(k + 3);
            if (k <= 5) {
                WAITV(5);                    // retire G(k) [+L(k+2) if any]
            } else if (k == 6) {
                WAITV(2);                    // retire G(6) (leaves G(7))
            } else {
                WAITV(0);                    // retire G(7)
            }
            commit(k);
        }
    } else {
        // ---- generic / inline-params fallback (r6-verified masked body) ----
        const float2* nb = noise + (size_t)b * N;
        for (int t = tid; t < N; t += nthr) {
            float4 p;
            if (INLINE_PARAMS) {
                float2 pm = pmeans[t];
                float scale = (float)(N - 1);
                p.x = __fmul_rn(__fdiv_rn(1.0f, __fadd_rn(1.0f, expf(-pm.x))), scale);
                p.y = __fmul_rn(__fdiv_rn(1.0f, __fadd_rn(1.0f, expf(-pm.y))), scale);
                float z  = __fadd_rn(psigmas[t], SIGMA_BOOST);
                float sp = __fadd_rn(fmaxf(z, 0.0f), log1pf(expf(-fabsf(z))));
                p.z = __fmul_rn(__fadd_rn(sp, EPSILON), (float)N);
                p.w = pvalues[t];
            } else {
                p = params[t];
            }
            float2 nz = nb[t];
            float s0 = __fadd_rn(p.x, __fmul_rn(p.z, nz.x));
            float s1 = __fadd_rn(p.y, __fmul_rn(p.z, nz.y));
            int row = (int)fminf(fmaxf(rintf(s0), 0.0f), fN1);
            int col = (int)fminf(fmaxf(rintf(s1), 0.0f), fN1);
            float xv = xb[col];
            float ctr = __fmul_rn(p.w, xv);
            bool lo = (row == 0);
            bool hi = (row == iN1);
            if (!(lo | hi)) atomicAdd(&ly[row], ctr);
            acc0 = __fadd_rn(acc0, lo ? ctr : 0.0f);
            accE = __fadd_rn(accE, hi ? ctr : 0.0f);
        }
    }

    // fold register accumulators: wave shfl-reduce, one atomic per wave
    for (int off = 32; off > 0; off >>= 1) {
        acc0 = __fadd_rn(acc0, __shfl_down(acc0, off, 64));
        accE = __fadd_rn(accE, __shfl_down(accE, off, 64));
    }
    if ((tid & 63) == 0) {
        atomicAdd(&ly[0], acc0);
        atomicAdd(&ly[iN1], accE);
    }
    __syncthreads();

    // coalesced nontemporal write-out of the full row
    const vfloat4* lv4 = (const vfloat4*)ly;
    vfloat4* yb4 = (vfloat4*)(y + (size_t)b * N);
    for (int i = tid; i < n4; i += nthr)
        __builtin_nontemporal_store(lv4[i], &yb4[i]);
}

extern "C" void kernel_launch(void* const* d_in, const int* in_sizes, int n_in,
                              void* d_out, int out_size, void* d_ws, size_t ws_size,
                              hipStream_t stream) {
    const float*  x       = (const float*)d_in[0];
    const float2* noise   = (const float2*)d_in[1];
    const float2* pmeans  = (const float2*)d_in[2];
    const float*  psigmas = (const float*)d_in[3];
    const float*  pvalues = (const float*)d_in[4];
    float* y = (float*)d_out;

    const int N = in_sizes[3];          // psigmas is (N,)
    const int B = in_sizes[0] / N;      // x is (B,N)

    const size_t params_bytes = (size_t)N * sizeof(float4);
    const bool use_ws = (ws_size >= params_bytes) && (d_ws != nullptr);

    const int block = 1024;
    const size_t lds_bytes = (size_t)N * sizeof(float);  // 64 KB at N=16384

    if (use_ws) {
        float4* params = (float4*)d_ws;
        params_kernel<<<(N + 255) / 256, 256, 0, stream>>>(pmeans, psigmas,
                                                           pvalues, params, N);
        contract_kernel<false><<<B, block, lds_bytes, stream>>>(
            x, noise, params, nullptr, nullptr, nullptr, y, N);
    } else {
        contract_kernel<true><<<B, block, lds_bytes, stream>>>(
            x, noise, nullptr, pmeans, psigmas, pvalues, y, N);
    }
}